// Round 6
// baseline (168.345 us; speedup 1.0000x reference)
//
#include <hip/hip_runtime.h>
#include <hip/hip_bf16.h>

#define TT 64
#define DD 255
#define KK 256
#define MM 512
#define CC 8
#define BB 4096
#define NB 4
#define TPB 32   // trees per block (grid.y splits the forest in 2)
#define TG 4     // trees staged per pass -> 8 passes

typedef _Float16 h2 __attribute__((ext_vector_type(2)));

__device__ __forceinline__ float wave_sum(float v) {
    v += __shfl_down(v, 32, 64);
    v += __shfl_down(v, 16, 64);
    v += __shfl_down(v, 8, 64);
    v += __shfl_down(v, 4, 64);
    v += __shfl_down(v, 2, 64);
    v += __shfl_down(v, 1, 64);
    return v;
}

// ---------------- kernel 0: extract feature index from one-hot W1 ----------
// One wave per (t,d) row: lanes read consecutive float4 -> fully coalesced.
__global__ void feat_kernel(const float* __restrict__ W1, int* __restrict__ feat) {
    const int row = blockIdx.x * 4 + (threadIdx.x >> 6);
    const int lane = threadIdx.x & 63;
    const float4* r = reinterpret_cast<const float4*>(W1 + (size_t)row * MM);
    float4 a = r[lane];
    float4 b = r[lane + 64];
    float ba = (float)(4 * lane);
    float bb = (float)(4 * (lane + 64));
    float acc = 0.0f;
    acc = fmaf(a.x, ba,        acc);
    acc = fmaf(a.y, ba + 1.0f, acc);
    acc = fmaf(a.z, ba + 2.0f, acc);
    acc = fmaf(a.w, ba + 3.0f, acc);
    acc = fmaf(b.x, bb,        acc);
    acc = fmaf(b.y, bb + 1.0f, acc);
    acc = fmaf(b.z, bb + 2.0f, acc);
    acc = fmaf(b.w, bb + 3.0f, acc);
    acc = wave_sum(acc);
    if (lane == 0) feat[row] = (int)(acc + 0.5f);
}

// s = sigmoid(10*(xv+b)) = 1/(1+2^(-10*log2(e)*(xv+b))); c1 = -14.4269504*b
__device__ __forceinline__ float sigm_from(float xv, float c1) {
    float earg = fmaf(-14.426950408889634f, xv, c1);
    float e = exp2f(earg);
    return __builtin_amdgcn_rcpf(1.0f + e);
}

// ---------------- kernel 1: forest forward -------------------------------
// grid (B/NB, 2): blockIdx.y -> 32-tree half; partials atomicAdd'ed into out.
// block: 256 threads = (leaf pair i in [0,128), sub in {0,1}); NB=4 batch rows.
// 8 passes x 4 trees; staged sigmoids packed fp16: s8[bl*2+sub][node] (h2 =
// tree pair), node stride 4B -> level-7 path reads conflict-free ds_read_b32.
// LDS ~17 KB -> 8-9 blocks/CU (vs 6 at R5's 25 KB): barrier stalls hidden by
// inter-block overlap. NO reg cap beyond (256,2) (R2/R4 lesson: caps->spills).
__global__ __launch_bounds__(256, 2) void forest_kernel(
        const float* __restrict__ x, const float* __restrict__ b1,
        const float* __restrict__ Cw, const int* __restrict__ feat,
        float* __restrict__ out) {
    __shared__ float xsi[MM][NB];            // 8 KB   [m][bl]
    __shared__ h2 s8[NB * 2 * 256];          // 8 KB   [bl*2+sub][node]
    __shared__ float red[4][NB][CC];         // 512 B

    const int tid = threadIdx.x;
    const int b0 = blockIdx.x * NB;
    const int t0 = blockIdx.y * TPB;

    // stage x rows, interleaved so one b128 gather serves all 4 rows
    for (int idx = tid; idx < MM * NB; idx += 256) {
        int m = idx & (MM - 1);
        int bl = idx >> 9;
        xsi[m][bl] = x[(size_t)(b0 + bl) * MM + m];
    }

    h2 acc[NB][4];   // [bl][class-pair] fp16 accumulators (16 regs)
    #pragma unroll
    for (int bl = 0; bl < NB; ++bl)
        #pragma unroll
        for (int q = 0; q < 4; ++q)
            acc[bl][q] = (h2){(_Float16)0.0f, (_Float16)0.0f};

    const int i = tid & 127;   // leaf pair: leaves 2i, 2i+1
    const int sub = tid >> 7;  // tree-pair subgroup (uniform per wave)
    const h2 one = {(_Float16)1.0f, (_Float16)1.0f};

    for (int g = 0; g < TPB / TG; ++g) {
        __syncthreads();
        // ---- stage sigmoids for 4 trees x 4 batch rows (fp16-packed) ----
        if (tid < DD) {
            const int d = tid;
            int f[TG];
            float c1[TG];
            #pragma unroll
            for (int j = 0; j < TG; ++j) {
                int t = t0 + g * TG + j;
                f[j] = feat[t * DD + d];
                c1[j] = -14.426950408889634f * b1[t * DD + d];
            }
            float sv[NB][TG];
            #pragma unroll
            for (int j = 0; j < TG; ++j) {
                float4 xv = *reinterpret_cast<const float4*>(&xsi[f[j]][0]);
                sv[0][j] = sigm_from(xv.x, c1[j]);
                sv[1][j] = sigm_from(xv.y, c1[j]);
                sv[2][j] = sigm_from(xv.z, c1[j]);
                sv[3][j] = sigm_from(xv.w, c1[j]);
            }
            #pragma unroll
            for (int bl = 0; bl < NB; ++bl) {
                s8[(bl * 2 + 0) * 256 + d] =
                    (h2){(_Float16)sv[bl][0], (_Float16)sv[bl][1]};
                s8[(bl * 2 + 1) * 256 + d] =
                    (h2){(_Float16)sv[bl][2], (_Float16)sv[bl][3]};
            }
        }
        __syncthreads();

        // ---- Cw for my 2 leaves x 2 trees, converted to packed fp16 ----
        h2 cwa[2][4], cwb[2][4];   // [tree][class-pair], leaves 2i / 2i+1
        #pragma unroll
        for (int j = 0; j < 2; ++j) {
            int t = t0 + g * TG + sub * 2 + j;
            const float4* p = reinterpret_cast<const float4*>(
                Cw + ((size_t)t * KK + 2 * i) * CC);
            float4 a0 = p[0], a1 = p[1], bv0 = p[2], bv1 = p[3];
            cwa[j][0] = (h2){(_Float16)a0.x, (_Float16)a0.y};
            cwa[j][1] = (h2){(_Float16)a0.z, (_Float16)a0.w};
            cwa[j][2] = (h2){(_Float16)a1.x, (_Float16)a1.y};
            cwa[j][3] = (h2){(_Float16)a1.z, (_Float16)a1.w};
            cwb[j][0] = (h2){(_Float16)bv0.x, (_Float16)bv0.y};
            cwb[j][1] = (h2){(_Float16)bv0.z, (_Float16)bv0.w};
            cwb[j][2] = (h2){(_Float16)bv1.x, (_Float16)bv1.y};
            cwb[j][3] = (h2){(_Float16)bv1.z, (_Float16)bv1.w};
        }

        // ---- path product in packed fp16 (2 trees/lane), 4 batch rows ----
        h2 pre[NB];
        #pragma unroll
        for (int bl = 0; bl < NB; ++bl) pre[bl] = one;

        #pragma unroll
        for (int lev = 0; lev < 7; ++lev) {
            int node = (1 << lev) - 1 + (i >> (7 - lev));
            int bit = (i >> (6 - lev)) & 1;
            _Float16 offs = (_Float16)(1 - bit);
            _Float16 sgs = (_Float16)(2 * bit - 1);    // bit? s : 1-s
            h2 offv = {offs, offs};
            h2 sg = {sgs, sgs};
            #pragma unroll
            for (int bl = 0; bl < NB; ++bl) {
                h2 s = s8[(bl * 2 + sub) * 256 + node];
                pre[bl] *= (sg * s + offv);
            }
        }
        const int node7 = 127 + i;
        #pragma unroll
        for (int bl = 0; bl < NB; ++bl) {
            h2 s = s8[(bl * 2 + sub) * 256 + node7];
            h2 pe = pre[bl] * (one - s);   // leaf 2i,   trees j0,j1
            h2 po = pre[bl] * s;           // leaf 2i+1, trees j0,j1
            #pragma unroll
            for (int q = 0; q < 4; ++q) {
                acc[bl][q] += (h2){pe.x, pe.x} * cwa[0][q];
                acc[bl][q] += (h2){po.x, po.x} * cwb[0][q];
                acc[bl][q] += (h2){pe.y, pe.y} * cwa[1][q];
                acc[bl][q] += (h2){po.y, po.y} * cwb[1][q];
            }
        }
    }

    // ---- block reduction: 32 partial sums (4 b x 8 classes), fp32 ----
    const int lane = tid & 63;
    const int wv = tid >> 6;
    float af[NB][CC];
    #pragma unroll
    for (int bl = 0; bl < NB; ++bl) {
        #pragma unroll
        for (int q = 0; q < 4; ++q) {
            af[bl][2 * q]     = wave_sum((float)acc[bl][q].x);
            af[bl][2 * q + 1] = wave_sum((float)acc[bl][q].y);
        }
    }
    if (lane == 0) {
        #pragma unroll
        for (int bl = 0; bl < NB; ++bl)
            #pragma unroll
            for (int c = 0; c < CC; ++c)
                red[wv][bl][c] = af[bl][c];
    }
    __syncthreads();
    if (tid < NB * CC) {
        int bl = tid >> 3;
        int c = tid & 7;
        float s = red[0][bl][c] + red[1][bl][c] + red[2][bl][c] + red[3][bl][c];
        atomicAdd(&out[(size_t)(b0 + bl) * CC + c], s * (1.0f / 64.0f));
    }
}

extern "C" void kernel_launch(void* const* d_in, const int* in_sizes, int n_in,
                              void* d_out, int out_size, void* d_ws, size_t ws_size,
                              hipStream_t stream) {
    const float* x  = (const float*)d_in[0];  // [B, M]
    const float* W1 = (const float*)d_in[1];  // [T, D, M] one-hot rows
    const float* b1 = (const float*)d_in[2];  // [T, D]
    // d_in[3] = Bpos, d_in[4] = Bneg: fixed complete-tree path masks (hardcoded)
    const float* Cw = (const float*)d_in[5];  // [T, K, C]
    float* out = (float*)d_out;               // [B, C] fp32
    int* feat = (int*)d_ws;                   // T*D ints, rebuilt every call

    hipMemsetAsync(out, 0, (size_t)BB * CC * sizeof(float), stream);
    feat_kernel<<<(TT * DD) / 4, 256, 0, stream>>>(W1, feat);
    forest_kernel<<<dim3(BB / NB, 2), 256, 0, stream>>>(x, b1, Cw, feat, out);
}

// Round 8
// 155.145 us; speedup vs baseline: 1.0851x; 1.0851x over previous
//
#include <hip/hip_runtime.h>
#include <hip/hip_bf16.h>

#define TT 64
#define DD 255
#define KK 256
#define MM 512
#define CC 8
#define BB 4096
#define RB 16    // rows per block = MFMA M
#define TPB 16   // trees per block (4 per wave)

typedef _Float16 h8 __attribute__((ext_vector_type(8)));
typedef _Float16 h2v __attribute__((ext_vector_type(2)));
typedef float f4 __attribute__((ext_vector_type(4)));

// cvt_pkrtz returns __fp16x2; bit-cast to our _Float16x2
__device__ __forceinline__ h2v pkrtz(float a, float b) {
    return __builtin_bit_cast(h2v, __builtin_amdgcn_cvt_pkrtz(a, b));
}

__device__ __forceinline__ float wave_sum(float v) {
    v += __shfl_down(v, 32, 64);
    v += __shfl_down(v, 16, 64);
    v += __shfl_down(v, 8, 64);
    v += __shfl_down(v, 4, 64);
    v += __shfl_down(v, 2, 64);
    v += __shfl_down(v, 1, 64);
    return v;
}

// ---------------- kernel 0: extract feature index from one-hot W1 ----------
__global__ void feat_kernel(const float* __restrict__ W1, int* __restrict__ feat) {
    const int row = blockIdx.x * 4 + (threadIdx.x >> 6);
    const int lane = threadIdx.x & 63;
    const float4* r = reinterpret_cast<const float4*>(W1 + (size_t)row * MM);
    float4 a = r[lane];
    float4 b = r[lane + 64];
    float ba = (float)(4 * lane);
    float bb = (float)(4 * (lane + 64));
    float acc = 0.0f;
    acc = fmaf(a.x, ba,        acc);
    acc = fmaf(a.y, ba + 1.0f, acc);
    acc = fmaf(a.z, ba + 2.0f, acc);
    acc = fmaf(a.w, ba + 3.0f, acc);
    acc = fmaf(b.x, bb,        acc);
    acc = fmaf(b.y, bb + 1.0f, acc);
    acc = fmaf(b.z, bb + 2.0f, acc);
    acc = fmaf(b.w, bb + 3.0f, acc);
    acc = wave_sum(acc);
    if (lane == 0) feat[row] = (int)(acc + 0.5f);
}

// s = sigmoid(10*(xv+b)) = 1/(1+2^(-10*log2(e)*(xv+b))); c1 = -14.4269504*b
__device__ __forceinline__ float sigm_from(float xv, float c1) {
    float earg = fmaf(-14.426950408889634f, xv, c1);
    float e = exp2f(earg);
    return __builtin_amdgcn_rcpf(1.0f + e);
}

// ---------------- kernel 1: forest forward, wave-autonomous + MFMA --------
// grid (B/16, T/16). Block = 16-row MFMA tile; wave w owns trees w*4..w*4+3
// with PRIVATE LDS slices (s8[w], cwl[w]) -> no __syncthreads in main loop
// (DS ops from one wave process in order; lgkmcnt fences at phase edges).
// Leaf probs are built per lane directly in MFMA A-frag layout
// (row=lane&15, k=(lane>>4)*8+j  [m120-verified]) via hierarchical DFS:
// levels 0-2 = chunk bits (compile-time), 3-4 = slot bits (lane-const),
// 5-7 expanded. Contraction = mfma_f32_16x16x32_f16, fp32 acc.
// D layout: col(class)=lane&15, row=(lane>>4)*4+reg  [m89/m91-verified].
__global__ __launch_bounds__(256, 2) void forest_kernel(
        const float* __restrict__ x, const float* __restrict__ b1,
        const float* __restrict__ Cw, const int* __restrict__ feat,
        float* __restrict__ out) {
    __shared__ _Float16 xsi[MM * RB];           // 16 KB [m][row] f16
    __shared__ _Float16 s8[4][256 * RB];        // 4x8 KB per-wave [node][row]
    __shared__ _Float16 cwl[4][8 * 8 * 4 * 8];  // 4x4 KB per-wave [c][n][slot][j]
    __shared__ f4 red[4][64];                   // 4 KB

    const int tid = threadIdx.x;
    const int w = tid >> 6;
    const int lane = tid & 63;
    const int b0 = blockIdx.x * RB;
    const int t0 = blockIdx.y * TPB;
    const int m = lane & 15;     // MFMA row (A) / class col (B) index
    const int slot = lane >> 4;  // MFMA k-slot

    // ---- xsi fill: x fp32 -> f16 [m][row]; coalesced float4 reads ----
    for (int e = tid; e < RB * MM / 4; e += 256) {
        int r = e >> 7;              // 128 float4 per row
        int m4 = (e & 127) << 2;
        float4 v = *reinterpret_cast<const float4*>(x + (size_t)(b0 + r) * MM + m4);
        xsi[(m4 + 0) * RB + r] = (_Float16)v.x;
        xsi[(m4 + 1) * RB + r] = (_Float16)v.y;
        xsi[(m4 + 2) * RB + r] = (_Float16)v.z;
        xsi[(m4 + 3) * RB + r] = (_Float16)v.w;
    }
    __syncthreads();   // barrier #1 (only one before epilogue)

    _Float16* s8w = s8[w];
    _Float16* cww = cwl[w];

    const int b3 = slot >> 1, b4 = slot & 1;
    const float sg3 = (float)(2 * b3 - 1), off3 = (float)(1 - b3);
    const float sg4 = (float)(2 * b4 - 1), off4 = (float)(1 - b4);

    f4 acc = {0.f, 0.f, 0.f, 0.f};

    for (int tt = 0; tt < 4; ++tt) {
        const int t = t0 + w * 4 + tt;
        asm volatile("" ::: "memory");  // keep prior reads before these writes

        // ---- sigmoid staging into wave-private s8w[node][row] ----
        #pragma unroll
        for (int kq = 0; kq < 4; ++kq) {
            int d = kq * 64 + lane;
            if (d < DD) {
                int f = feat[t * DD + d];
                float c1 = -14.426950408889634f * b1[t * DD + d];
                const float4* xp = reinterpret_cast<const float4*>(xsi + f * RB);
                float4 A = xp[0], Bv = xp[1];
                float s[16];
                h2v u;
                u = __builtin_bit_cast(h2v, A.x);  s[0] = sigm_from((float)u.x, c1);  s[1] = sigm_from((float)u.y, c1);
                u = __builtin_bit_cast(h2v, A.y);  s[2] = sigm_from((float)u.x, c1);  s[3] = sigm_from((float)u.y, c1);
                u = __builtin_bit_cast(h2v, A.z);  s[4] = sigm_from((float)u.x, c1);  s[5] = sigm_from((float)u.y, c1);
                u = __builtin_bit_cast(h2v, A.w);  s[6] = sigm_from((float)u.x, c1);  s[7] = sigm_from((float)u.y, c1);
                u = __builtin_bit_cast(h2v, Bv.x); s[8] = sigm_from((float)u.x, c1);  s[9] = sigm_from((float)u.y, c1);
                u = __builtin_bit_cast(h2v, Bv.y); s[10] = sigm_from((float)u.x, c1); s[11] = sigm_from((float)u.y, c1);
                u = __builtin_bit_cast(h2v, Bv.z); s[12] = sigm_from((float)u.x, c1); s[13] = sigm_from((float)u.y, c1);
                u = __builtin_bit_cast(h2v, Bv.w); s[14] = sigm_from((float)u.x, c1); s[15] = sigm_from((float)u.y, c1);
                float4 W0, W1;
                W0.x = __builtin_bit_cast(float, pkrtz(s[0], s[1]));
                W0.y = __builtin_bit_cast(float, pkrtz(s[2], s[3]));
                W0.z = __builtin_bit_cast(float, pkrtz(s[4], s[5]));
                W0.w = __builtin_bit_cast(float, pkrtz(s[6], s[7]));
                W1.x = __builtin_bit_cast(float, pkrtz(s[8], s[9]));
                W1.y = __builtin_bit_cast(float, pkrtz(s[10], s[11]));
                W1.z = __builtin_bit_cast(float, pkrtz(s[12], s[13]));
                W1.w = __builtin_bit_cast(float, pkrtz(s[14], s[15]));
                *reinterpret_cast<float4*>(s8w + d * RB) = W0;
                *reinterpret_cast<float4*>(s8w + d * RB + 8) = W1;
            }
        }

        // ---- Cw staging into wave-private B-frag order [c][n][slot][j] ----
        #pragma unroll
        for (int kq = 0; kq < 4; ++kq) {
            int k = kq * 64 + lane;
            const float4* cp = reinterpret_cast<const float4*>(Cw + ((size_t)t * KK + k) * CC);
            float4 p0 = cp[0], p1 = cp[1];
            int cc = k >> 5, sl = (k >> 3) & 3, j = k & 7;
            _Float16* bp = cww + ((cc * 8) * 4 + sl) * 8 + j;  // n stride = 32 halfs
            bp[0 * 32] = (_Float16)p0.x;
            bp[1 * 32] = (_Float16)p0.y;
            bp[2 * 32] = (_Float16)p0.z;
            bp[3 * 32] = (_Float16)p0.w;
            bp[4 * 32] = (_Float16)p1.x;
            bp[5 * 32] = (_Float16)p1.y;
            bp[6 * 32] = (_Float16)p1.z;
            bp[7 * 32] = (_Float16)p1.w;
        }
        asm volatile("s_waitcnt lgkmcnt(0)" ::: "memory");  // wave-local fence

        // ---- depth-0..2 prefix products (8 of them, one per chunk) ----
        float s0 = (float)s8w[0 * RB + m];
        float s1 = (float)s8w[1 * RB + m];
        float s2 = (float)s8w[2 * RB + m];
        float s3 = (float)s8w[3 * RB + m];
        float s4 = (float)s8w[4 * RB + m];
        float s5p = (float)s8w[5 * RB + m];
        float s6 = (float)s8w[6 * RB + m];
        float P10 = 1.0f - s0, P11 = s0;
        float P200 = P10 * (1.0f - s1), P201 = P10 * s1;
        float P210 = P11 * (1.0f - s2), P211 = P11 * s2;
        float P3a[8];
        P3a[0] = P200 * (1.0f - s3); P3a[1] = P200 * s3;
        P3a[2] = P201 * (1.0f - s4); P3a[3] = P201 * s4;
        P3a[4] = P210 * (1.0f - s5p); P3a[5] = P210 * s5p;
        P3a[6] = P211 * (1.0f - s6); P3a[7] = P211 * s6;

        // ---- 8 chunks: DFS expand levels 3..7, emit A-frag, MFMA ----
        #pragma unroll
        for (int c = 0; c < 8; ++c) {
            const int n3 = 7 + c;                       // depth-3 node (compile-time)
            float sc3 = (float)s8w[n3 * RB + m];
            float f3 = fmaf(sg3, sc3, off3);
            int n4 = 2 * n3 + 1 + b3;
            float sc4 = (float)s8w[n4 * RB + m];
            float f4v = fmaf(sg4, sc4, off4);
            float P5 = P3a[c] * f3 * f4v;
            int n5 = 2 * n4 + 1 + b4;                   // octet root (depth 5)
            float s5 = (float)s8w[n5 * RB + m];
            float v1 = P5 * s5, v0 = P5 - v1;
            int q0 = 2 * n5 + 1;
            float sq0 = (float)s8w[q0 * RB + m];
            float sq1 = (float)s8w[(q0 + 1) * RB + m];
            float w01 = v0 * sq0, w00 = v0 - w01;
            float w11 = v1 * sq1, w10 = v1 - w11;
            int r0 = 2 * q0 + 1;                        // 4 consecutive depth-7 nodes
            float sr0 = (float)s8w[(r0 + 0) * RB + m];
            float sr1 = (float)s8w[(r0 + 1) * RB + m];
            float sr2 = (float)s8w[(r0 + 2) * RB + m];
            float sr3 = (float)s8w[(r0 + 3) * RB + m];
            float l1 = w00 * sr0, l0 = w00 - l1;
            float l3 = w01 * sr1, l2 = w01 - l3;
            float l5 = w10 * sr2, l4 = w10 - l5;
            float l7 = w11 * sr3, l6 = w11 - l7;
            union { h8 v; h2v p[4]; } U;
            U.p[0] = pkrtz(l0, l1);
            U.p[1] = pkrtz(l2, l3);
            U.p[2] = pkrtz(l4, l5);
            U.p[3] = pkrtz(l6, l7);
            h8 bf = {};
            if (m < CC)
                bf = *reinterpret_cast<const h8*>(cww + ((c * 8 + m) * 4 + slot) * 8);
            acc = __builtin_amdgcn_mfma_f32_16x16x32_f16(U.v, bf, acc, 0, 0, 0);
        }
    }

    // ---- cross-wave reduction (waves hold disjoint trees) ----
    red[w][lane] = acc;
    __syncthreads();   // barrier #2
    if (tid < 64) {
        f4 sum = red[0][tid];
        sum += red[1][tid];
        sum += red[2][tid];
        sum += red[3][tid];
        int n = tid & 15, sl = tid >> 4;
        if (n < CC) {
            #pragma unroll
            for (int reg = 0; reg < 4; ++reg) {
                int row = sl * 4 + reg;                  // D: row=(lane>>4)*4+reg
                atomicAdd(&out[(size_t)(b0 + row) * CC + n], sum[reg] * (1.0f / 64.0f));
            }
        }
    }
}

extern "C" void kernel_launch(void* const* d_in, const int* in_sizes, int n_in,
                              void* d_out, int out_size, void* d_ws, size_t ws_size,
                              hipStream_t stream) {
    const float* x  = (const float*)d_in[0];  // [B, M]
    const float* W1 = (const float*)d_in[1];  // [T, D, M] one-hot rows
    const float* b1 = (const float*)d_in[2];  // [T, D]
    // d_in[3] = Bpos, d_in[4] = Bneg: fixed complete-tree path masks (hardcoded)
    const float* Cw = (const float*)d_in[5];  // [T, K, C]
    float* out = (float*)d_out;               // [B, C] fp32
    int* feat = (int*)d_ws;                   // T*D ints, rebuilt every call

    (void)hipMemsetAsync(out, 0, (size_t)BB * CC * sizeof(float), stream);
    feat_kernel<<<(TT * DD) / 4, 256, 0, stream>>>(W1, feat);
    forest_kernel<<<dim3(BB / RB, TT / TPB), 256, 0, stream>>>(x, b1, Cw, feat, out);
}

// Round 9
// 147.666 us; speedup vs baseline: 1.1400x; 1.0506x over previous
//
#include <hip/hip_runtime.h>
#include <hip/hip_bf16.h>

#define TT 64
#define DD 255
#define KK 256
#define MM 512
#define CC 8
#define BB 4096
#define RB 16    // rows per block = MFMA M
#define TPB 16   // trees per block (4 per wave)
#define ST 18    // odd-dword LDS stride (halfs) for xsi rows & s8 nodes

typedef _Float16 h8 __attribute__((ext_vector_type(8)));
typedef _Float16 h2v __attribute__((ext_vector_type(2)));
typedef float f4 __attribute__((ext_vector_type(4)));

// cvt_pkrtz returns __fp16x2; bit-cast to our _Float16x2
__device__ __forceinline__ h2v pkrtz(float a, float b) {
    return __builtin_bit_cast(h2v, __builtin_amdgcn_cvt_pkrtz(a, b));
}

__device__ __forceinline__ float wave_sum(float v) {
    v += __shfl_down(v, 32, 64);
    v += __shfl_down(v, 16, 64);
    v += __shfl_down(v, 8, 64);
    v += __shfl_down(v, 4, 64);
    v += __shfl_down(v, 2, 64);
    v += __shfl_down(v, 1, 64);
    return v;
}

// ---------------- kernel 0: extract feature index from one-hot W1 ----------
__global__ void feat_kernel(const float* __restrict__ W1, int* __restrict__ feat) {
    const int row = blockIdx.x * 4 + (threadIdx.x >> 6);
    const int lane = threadIdx.x & 63;
    const float4* r = reinterpret_cast<const float4*>(W1 + (size_t)row * MM);
    float4 a = r[lane];
    float4 b = r[lane + 64];
    float ba = (float)(4 * lane);
    float bb = (float)(4 * (lane + 64));
    float acc = 0.0f;
    acc = fmaf(a.x, ba,        acc);
    acc = fmaf(a.y, ba + 1.0f, acc);
    acc = fmaf(a.z, ba + 2.0f, acc);
    acc = fmaf(a.w, ba + 3.0f, acc);
    acc = fmaf(b.x, bb,        acc);
    acc = fmaf(b.y, bb + 1.0f, acc);
    acc = fmaf(b.z, bb + 2.0f, acc);
    acc = fmaf(b.w, bb + 3.0f, acc);
    acc = wave_sum(acc);
    if (lane == 0) feat[row] = (int)(acc + 0.5f);
}

// s = sigmoid(10*(xv+b)) = 1/(1+2^(-10*log2(e)*(xv+b))); c1 = -14.4269504*b
__device__ __forceinline__ float sigm_from(float xv, float c1) {
    float earg = fmaf(-14.426950408889634f, xv, c1);
    float e = exp2f(earg);
    return __builtin_amdgcn_rcpf(1.0f + e);
}

// ---------------- kernel 1: forest forward, wave-autonomous + MFMA --------
// R8 structure; R9 = odd-stride banking. ST=18 halfs (9 dwords, odd):
//  - s8 staging writes: 8x ds_write_b32 at dword d*9+i -> gcd(9,32)=1, 2-way max
//  - xsi gather reads:  8x ds_read_b32 at dword f*9+i -> random f ~2-way avg
//  - cwl slot dim padded 4->5: write banks spread, b128 reads stay 16B-aligned
// A-frag: row=lane&15, k=(lane>>4)*8+j [m120]; D: col=lane&15, row=quad*4+reg.
__global__ __launch_bounds__(256, 2) void forest_kernel(
        const float* __restrict__ x, const float* __restrict__ b1,
        const float* __restrict__ Cw, const int* __restrict__ feat,
        float* __restrict__ out) {
    __shared__ _Float16 xsi[MM * ST];                  // 18 KB [m][row(16)+pad]
    __shared__ _Float16 s8[4][256 * ST];               // 36 KB per-wave [node][row+pad]
    __shared__ __align__(16) _Float16 cwl[4][8 * 8 * 5 * 8];  // 20 KB [c][n][slot(5)][j]
    __shared__ f4 red[4][64];                          // 4 KB

    const int tid = threadIdx.x;
    const int w = tid >> 6;
    const int lane = tid & 63;
    const int b0 = blockIdx.x * RB;
    const int t0 = blockIdx.y * TPB;
    const int m = lane & 15;     // MFMA row (A) / class col (B) index
    const int slot = lane >> 4;  // MFMA k-slot

    // ---- xsi fill: scalar f32->f16, write u16 at dword m*9 (bank-spread) ----
    for (int idx = tid; idx < MM * RB; idx += 256) {
        int mm = idx & (MM - 1);
        int r = idx >> 9;
        xsi[mm * ST + r] = (_Float16)x[(size_t)(b0 + r) * MM + mm];
    }
    __syncthreads();   // barrier #1

    _Float16* s8w = s8[w];
    _Float16* cww = cwl[w];

    const int b3 = slot >> 1, b4 = slot & 1;
    const float sg3 = (float)(2 * b3 - 1), off3 = (float)(1 - b3);
    const float sg4 = (float)(2 * b4 - 1), off4 = (float)(1 - b4);

    f4 acc = {0.f, 0.f, 0.f, 0.f};

    for (int tt = 0; tt < 4; ++tt) {
        const int t = t0 + w * 4 + tt;
        asm volatile("" ::: "memory");  // keep prior reads before these writes

        // ---- sigmoid staging into wave-private s8w[node][row], b32 I/O ----
        #pragma unroll
        for (int kq = 0; kq < 4; ++kq) {
            int d = kq * 64 + lane;
            if (d < DD) {
                int f = feat[t * DD + d];
                float c1 = -14.426950408889634f * b1[t * DD + d];
                const uint32_t* xp = reinterpret_cast<const uint32_t*>(xsi + f * ST);
                uint32_t* sp = reinterpret_cast<uint32_t*>(s8w + d * ST);
                #pragma unroll
                for (int i2 = 0; i2 < 8; ++i2) {
                    h2v u = __builtin_bit_cast(h2v, xp[i2]);
                    float sa = sigm_from((float)u.x, c1);
                    float sb = sigm_from((float)u.y, c1);
                    sp[i2] = __builtin_bit_cast(uint32_t, pkrtz(sa, sb));
                }
            }
        }

        // ---- Cw staging into wave-private B-frag order [c][n][slot(5)][j] ----
        #pragma unroll
        for (int kq = 0; kq < 4; ++kq) {
            int k = kq * 64 + lane;
            const float4* cp = reinterpret_cast<const float4*>(Cw + ((size_t)t * KK + k) * CC);
            float4 p0 = cp[0], p1 = cp[1];
            int cc = k >> 5, sl = (k >> 3) & 3, j = k & 7;
            _Float16* bp = cww + cc * 320 + sl * 8 + j;   // n stride = 40 halfs
            bp[0 * 40] = (_Float16)p0.x;
            bp[1 * 40] = (_Float16)p0.y;
            bp[2 * 40] = (_Float16)p0.z;
            bp[3 * 40] = (_Float16)p0.w;
            bp[4 * 40] = (_Float16)p1.x;
            bp[5 * 40] = (_Float16)p1.y;
            bp[6 * 40] = (_Float16)p1.z;
            bp[7 * 40] = (_Float16)p1.w;
        }
        asm volatile("s_waitcnt lgkmcnt(0)" ::: "memory");  // wave-local fence

        // ---- depth-0..2 prefix products (8 of them, one per chunk) ----
        float s0 = (float)s8w[0 * ST + m];
        float s1 = (float)s8w[1 * ST + m];
        float s2 = (float)s8w[2 * ST + m];
        float s3 = (float)s8w[3 * ST + m];
        float s4 = (float)s8w[4 * ST + m];
        float s5p = (float)s8w[5 * ST + m];
        float s6 = (float)s8w[6 * ST + m];
        float P10 = 1.0f - s0, P11 = s0;
        float P200 = P10 * (1.0f - s1), P201 = P10 * s1;
        float P210 = P11 * (1.0f - s2), P211 = P11 * s2;
        float P3a[8];
        P3a[0] = P200 * (1.0f - s3); P3a[1] = P200 * s3;
        P3a[2] = P201 * (1.0f - s4); P3a[3] = P201 * s4;
        P3a[4] = P210 * (1.0f - s5p); P3a[5] = P210 * s5p;
        P3a[6] = P211 * (1.0f - s6); P3a[7] = P211 * s6;

        // ---- 8 chunks: DFS expand levels 3..7, emit A-frag, MFMA ----
        #pragma unroll
        for (int c = 0; c < 8; ++c) {
            const int n3 = 7 + c;                       // depth-3 node (compile-time)
            float sc3 = (float)s8w[n3 * ST + m];
            float f3 = fmaf(sg3, sc3, off3);
            int n4 = 2 * n3 + 1 + b3;
            float sc4 = (float)s8w[n4 * ST + m];
            float f4v = fmaf(sg4, sc4, off4);
            float P5 = P3a[c] * f3 * f4v;
            int n5 = 2 * n4 + 1 + b4;                   // octet root (depth 5)
            float s5 = (float)s8w[n5 * ST + m];
            float v1 = P5 * s5, v0 = P5 - v1;
            int q0 = 2 * n5 + 1;
            float sq0 = (float)s8w[q0 * ST + m];
            float sq1 = (float)s8w[(q0 + 1) * ST + m];
            float w01 = v0 * sq0, w00 = v0 - w01;
            float w11 = v1 * sq1, w10 = v1 - w11;
            int r0 = 2 * q0 + 1;                        // 4 consecutive depth-7 nodes
            float sr0 = (float)s8w[(r0 + 0) * ST + m];
            float sr1 = (float)s8w[(r0 + 1) * ST + m];
            float sr2 = (float)s8w[(r0 + 2) * ST + m];
            float sr3 = (float)s8w[(r0 + 3) * ST + m];
            float l1 = w00 * sr0, l0 = w00 - l1;
            float l3 = w01 * sr1, l2 = w01 - l3;
            float l5 = w10 * sr2, l4 = w10 - l5;
            float l7 = w11 * sr3, l6 = w11 - l7;
            union { h8 v; h2v p[4]; } U;
            U.p[0] = pkrtz(l0, l1);
            U.p[1] = pkrtz(l2, l3);
            U.p[2] = pkrtz(l4, l5);
            U.p[3] = pkrtz(l6, l7);
            h8 bf = {};
            if (m < CC)
                bf = *reinterpret_cast<const h8*>(cww + (c * 8 + m) * 40 + slot * 8);
            acc = __builtin_amdgcn_mfma_f32_16x16x32_f16(U.v, bf, acc, 0, 0, 0);
        }
    }

    // ---- cross-wave reduction (waves hold disjoint trees) ----
    red[w][lane] = acc;
    __syncthreads();   // barrier #2
    if (tid < 64) {
        f4 sum = red[0][tid];
        sum += red[1][tid];
        sum += red[2][tid];
        sum += red[3][tid];
        int n = tid & 15, sl = tid >> 4;
        if (n < CC) {
            #pragma unroll
            for (int reg = 0; reg < 4; ++reg) {
                int row = sl * 4 + reg;                  // D: row=(lane>>4)*4+reg
                atomicAdd(&out[(size_t)(b0 + row) * CC + n], sum[reg] * (1.0f / 64.0f));
            }
        }
    }
}

extern "C" void kernel_launch(void* const* d_in, const int* in_sizes, int n_in,
                              void* d_out, int out_size, void* d_ws, size_t ws_size,
                              hipStream_t stream) {
    const float* x  = (const float*)d_in[0];  // [B, M]
    const float* W1 = (const float*)d_in[1];  // [T, D, M] one-hot rows
    const float* b1 = (const float*)d_in[2];  // [T, D]
    // d_in[3] = Bpos, d_in[4] = Bneg: fixed complete-tree path masks (hardcoded)
    const float* Cw = (const float*)d_in[5];  // [T, K, C]
    float* out = (float*)d_out;               // [B, C] fp32
    int* feat = (int*)d_ws;                   // T*D ints, rebuilt every call

    (void)hipMemsetAsync(out, 0, (size_t)BB * CC * sizeof(float), stream);
    feat_kernel<<<(TT * DD) / 4, 256, 0, stream>>>(W1, feat);
    forest_kernel<<<dim3(BB / RB, TT / TPB), 256, 0, stream>>>(x, b1, Cw, feat, out);
}

// Round 10
// 147.369 us; speedup vs baseline: 1.1423x; 1.0020x over previous
//
#include <hip/hip_runtime.h>
#include <hip/hip_bf16.h>

#define TT 64
#define DD 255
#define KK 256
#define MM 512
#define CC 8
#define BB 4096
#define RB 16    // rows per block = MFMA M
#define TPB 16   // trees per block (4 per wave)
#define ST 18    // s8 node stride in halfs (9 dwords, odd -> bank-spread)

typedef _Float16 h8 __attribute__((ext_vector_type(8)));
typedef _Float16 h2v __attribute__((ext_vector_type(2)));
typedef float f4 __attribute__((ext_vector_type(4)));

// cvt_pkrtz returns __fp16x2; bit-cast to our _Float16x2
__device__ __forceinline__ h2v pkrtz(float a, float b) {
    return __builtin_bit_cast(h2v, __builtin_amdgcn_cvt_pkrtz(a, b));
}

__device__ __forceinline__ float wave_sum(float v) {
    v += __shfl_down(v, 32, 64);
    v += __shfl_down(v, 16, 64);
    v += __shfl_down(v, 8, 64);
    v += __shfl_down(v, 4, 64);
    v += __shfl_down(v, 2, 64);
    v += __shfl_down(v, 1, 64);
    return v;
}

// ---------------- kernel 0: extract feature index from one-hot W1 ----------
__global__ void feat_kernel(const float* __restrict__ W1, int* __restrict__ feat) {
    const int row = blockIdx.x * 4 + (threadIdx.x >> 6);
    const int lane = threadIdx.x & 63;
    const float4* r = reinterpret_cast<const float4*>(W1 + (size_t)row * MM);
    float4 a = r[lane];
    float4 b = r[lane + 64];
    float ba = (float)(4 * lane);
    float bb = (float)(4 * (lane + 64));
    float acc = 0.0f;
    acc = fmaf(a.x, ba,        acc);
    acc = fmaf(a.y, ba + 1.0f, acc);
    acc = fmaf(a.z, ba + 2.0f, acc);
    acc = fmaf(a.w, ba + 3.0f, acc);
    acc = fmaf(b.x, bb,        acc);
    acc = fmaf(b.y, bb + 1.0f, acc);
    acc = fmaf(b.z, bb + 2.0f, acc);
    acc = fmaf(b.w, bb + 3.0f, acc);
    acc = wave_sum(acc);
    if (lane == 0) feat[row] = (int)(acc + 0.5f);
}

// ---------------- kernel 0b: Cw -> f16 B-frag order in global ws ----------
// cwT[(((t*8+c)*8+cls)*4+slot)*8+j] = Cw[t][c*32+slot*8+j][cls]  (256 KB)
// Thread per (t,k); 8 consecutive-j threads write 16B-contiguous -> coalesced.
__global__ void cwt_kernel(const float* __restrict__ Cw, _Float16* __restrict__ cwT) {
    int idx = blockIdx.x * 256 + threadIdx.x;   // t*256 + k
    int t = idx >> 8, k = idx & 255;
    int c = k >> 5, sl = (k >> 3) & 3, j = k & 7;
    const float4* p = reinterpret_cast<const float4*>(Cw + (size_t)idx * CC);
    float4 p0 = p[0], p1 = p[1];
    _Float16* base = cwT + ((((t * 8 + c) * 8) * 4 + sl) * 8 + j);  // cls stride 32
    base[0 * 32] = (_Float16)p0.x;
    base[1 * 32] = (_Float16)p0.y;
    base[2 * 32] = (_Float16)p0.z;
    base[3 * 32] = (_Float16)p0.w;
    base[4 * 32] = (_Float16)p1.x;
    base[5 * 32] = (_Float16)p1.y;
    base[6 * 32] = (_Float16)p1.z;
    base[7 * 32] = (_Float16)p1.w;
}

// s = sigmoid(10*(xv+b)) = 1/(1+2^(-10*log2(e)*(xv+b))); c1 = -14.4269504*b
__device__ __forceinline__ float sigm_from(float xv, float c1) {
    float earg = fmaf(-14.426950408889634f, xv, c1);
    float e = exp2f(earg);
    return __builtin_amdgcn_rcpf(1.0f + e);
}

// ---------------- kernel 1: forest forward, wave-autonomous + MFMA --------
// R9 structure; R10: cwl LDS removed (global cwT b128 loads, L2-resident),
// xsi paired-17-dword layout (17 KB), red aliased into xsi. LDS 54272 B
// -> 3 blocks/CU (12 waves, was 8). s8 ST=18 unchanged (proven banking).
// A-frag: row=lane&15, k=(lane>>4)*8+j [m120]; D: col=lane&15, row=quad*4+reg.
__global__ __launch_bounds__(256, 2) void forest_kernel(
        const float* __restrict__ x, const float* __restrict__ b1,
        const _Float16* __restrict__ cwT, const int* __restrict__ feat,
        float* __restrict__ out) {
    // feature f lives at dword (17*f)>>1 (8 dwords = 16 rows; pairs share 17 dwords)
    __shared__ __align__(16) _Float16 xsi[(MM / 2) * 34];   // 17408 B
    __shared__ _Float16 s8[4][256 * ST];                    // 36864 B
    // red[4][64] f4 aliased into xsi at epilogue (after full-block barrier)

    const int tid = threadIdx.x;
    const int w = tid >> 6;
    const int lane = tid & 63;
    const int b0 = blockIdx.x * RB;
    const int t0 = blockIdx.y * TPB;
    const int m = lane & 15;     // MFMA row (A) / class col (B) index
    const int slot = lane >> 4;  // MFMA k-slot

    // ---- xsi fill: scalar f32->f16 at half (17*f - (f&1) + r) ----
    for (int idx = tid; idx < MM * RB; idx += 256) {
        int mm = idx & (MM - 1);
        int r = idx >> 9;
        xsi[17 * mm - (mm & 1) + r] = (_Float16)x[(size_t)(b0 + r) * MM + mm];
    }
    __syncthreads();   // barrier #1

    _Float16* s8w = s8[w];

    const int b3 = slot >> 1, b4 = slot & 1;
    const float sg3 = (float)(2 * b3 - 1), off3 = (float)(1 - b3);
    const float sg4 = (float)(2 * b4 - 1), off4 = (float)(1 - b4);

    f4 acc = {0.f, 0.f, 0.f, 0.f};

    for (int tt = 0; tt < 4; ++tt) {
        const int t = t0 + w * 4 + tt;
        asm volatile("" ::: "memory");  // keep prior reads before these writes

        // ---- sigmoid staging into wave-private s8w[node][row], b32 I/O ----
        #pragma unroll
        for (int kq = 0; kq < 4; ++kq) {
            int d = kq * 64 + lane;
            if (d < DD) {
                int f = feat[t * DD + d];
                float c1 = -14.426950408889634f * b1[t * DD + d];
                const uint32_t* xp = reinterpret_cast<const uint32_t*>(xsi) + ((17 * f) >> 1);
                uint32_t* sp = reinterpret_cast<uint32_t*>(s8w + d * ST);
                #pragma unroll
                for (int i2 = 0; i2 < 8; ++i2) {
                    h2v u = __builtin_bit_cast(h2v, xp[i2]);
                    float sa = sigm_from((float)u.x, c1);
                    float sb = sigm_from((float)u.y, c1);
                    sp[i2] = __builtin_bit_cast(uint32_t, pkrtz(sa, sb));
                }
            }
        }

        // ---- B-frags from global cwT (L2-resident, coalesced b128) ----
        h8 bfr[8] = {};
        if (m < CC) {
            const h8* cp = reinterpret_cast<const h8*>(cwT) +
                           (((t * 8 + 0) * 8 + m) * 4 + slot);
            #pragma unroll
            for (int c = 0; c < 8; ++c) bfr[c] = cp[c * 32];  // chunk stride 32 h8
        }
        asm volatile("s_waitcnt lgkmcnt(0)" ::: "memory");  // wave-local fence

        // ---- depth-0..2 prefix products (8 of them, one per chunk) ----
        float s0 = (float)s8w[0 * ST + m];
        float s1 = (float)s8w[1 * ST + m];
        float s2 = (float)s8w[2 * ST + m];
        float s3 = (float)s8w[3 * ST + m];
        float s4 = (float)s8w[4 * ST + m];
        float s5p = (float)s8w[5 * ST + m];
        float s6 = (float)s8w[6 * ST + m];
        float P10 = 1.0f - s0, P11 = s0;
        float P200 = P10 * (1.0f - s1), P201 = P10 * s1;
        float P210 = P11 * (1.0f - s2), P211 = P11 * s2;
        float P3a[8];
        P3a[0] = P200 * (1.0f - s3); P3a[1] = P200 * s3;
        P3a[2] = P201 * (1.0f - s4); P3a[3] = P201 * s4;
        P3a[4] = P210 * (1.0f - s5p); P3a[5] = P210 * s5p;
        P3a[6] = P211 * (1.0f - s6); P3a[7] = P211 * s6;

        // ---- 8 chunks: DFS expand levels 3..7, emit A-frag, MFMA ----
        #pragma unroll
        for (int c = 0; c < 8; ++c) {
            const int n3 = 7 + c;                       // depth-3 node (compile-time)
            float sc3 = (float)s8w[n3 * ST + m];
            float f3 = fmaf(sg3, sc3, off3);
            int n4 = 2 * n3 + 1 + b3;
            float sc4 = (float)s8w[n4 * ST + m];
            float f4v = fmaf(sg4, sc4, off4);
            float P5 = P3a[c] * f3 * f4v;
            int n5 = 2 * n4 + 1 + b4;                   // octet root (depth 5)
            float s5 = (float)s8w[n5 * ST + m];
            float v1 = P5 * s5, v0 = P5 - v1;
            int q0 = 2 * n5 + 1;
            float sq0 = (float)s8w[q0 * ST + m];
            float sq1 = (float)s8w[(q0 + 1) * ST + m];
            float w01 = v0 * sq0, w00 = v0 - w01;
            float w11 = v1 * sq1, w10 = v1 - w11;
            int r0 = 2 * q0 + 1;                        // 4 consecutive depth-7 nodes
            float sr0 = (float)s8w[(r0 + 0) * ST + m];
            float sr1 = (float)s8w[(r0 + 1) * ST + m];
            float sr2 = (float)s8w[(r0 + 2) * ST + m];
            float sr3 = (float)s8w[(r0 + 3) * ST + m];
            float l1 = w00 * sr0, l0 = w00 - l1;
            float l3 = w01 * sr1, l2 = w01 - l3;
            float l5 = w10 * sr2, l4 = w10 - l5;
            float l7 = w11 * sr3, l6 = w11 - l7;
            union { h8 v; h2v p[4]; } U;
            U.p[0] = pkrtz(l0, l1);
            U.p[1] = pkrtz(l2, l3);
            U.p[2] = pkrtz(l4, l5);
            U.p[3] = pkrtz(l6, l7);
            acc = __builtin_amdgcn_mfma_f32_16x16x32_f16(U.v, bfr[c], acc, 0, 0, 0);
        }
    }

    // ---- cross-wave reduction; red aliased into xsi (dead after main loop) ----
    __syncthreads();   // all waves done with xsi/s8 before alias write
    f4* red = reinterpret_cast<f4*>(xsi);
    red[w * 64 + lane] = acc;
    __syncthreads();   // barrier #2
    if (tid < 64) {
        f4 sum = red[0 * 64 + tid];
        sum += red[1 * 64 + tid];
        sum += red[2 * 64 + tid];
        sum += red[3 * 64 + tid];
        int n = tid & 15, sl = tid >> 4;
        if (n < CC) {
            #pragma unroll
            for (int reg = 0; reg < 4; ++reg) {
                int row = sl * 4 + reg;                  // D: row=(lane>>4)*4+reg
                atomicAdd(&out[(size_t)(b0 + row) * CC + n], sum[reg] * (1.0f / 64.0f));
            }
        }
    }
}

extern "C" void kernel_launch(void* const* d_in, const int* in_sizes, int n_in,
                              void* d_out, int out_size, void* d_ws, size_t ws_size,
                              hipStream_t stream) {
    const float* x  = (const float*)d_in[0];  // [B, M]
    const float* W1 = (const float*)d_in[1];  // [T, D, M] one-hot rows
    const float* b1 = (const float*)d_in[2];  // [T, D]
    // d_in[3] = Bpos, d_in[4] = Bneg: fixed complete-tree path masks (hardcoded)
    const float* Cw = (const float*)d_in[5];  // [T, K, C]
    float* out = (float*)d_out;               // [B, C] fp32

    // ws layout: cwT f16 [256 KB] | feat int [65 KB]  (rebuilt every call)
    _Float16* cwT = (_Float16*)d_ws;
    int* feat = (int*)((char*)d_ws + (size_t)TT * KK * CC * sizeof(_Float16));

    (void)hipMemsetAsync(out, 0, (size_t)BB * CC * sizeof(float), stream);
    feat_kernel<<<(TT * DD) / 4, 256, 0, stream>>>(W1, feat);
    cwt_kernel<<<(TT * KK) / 256, 256, 0, stream>>>(Cw, cwT);
    forest_kernel<<<dim3(BB / RB, TT / TPB), 256, 0, stream>>>(x, b1, cwT, feat, out);
}

// Round 12
// 141.710 us; speedup vs baseline: 1.1880x; 1.0399x over previous
//
#include <hip/hip_runtime.h>
#include <hip/hip_bf16.h>

#define TT 64
#define DD 255
#define KK 256
#define MM 512
#define CC 8
#define BB 4096
#define RB 16    // rows per block = MFMA M
#define TPB 16   // trees per block (4 per wave)
#define ST 18    // s8 node stride in halfs (9 dwords, odd -> bank-spread)
#define XS 16    // xsi feature stride in halfs (32B, 16B-aligned -> b128 gather)

typedef _Float16 h8 __attribute__((ext_vector_type(8)));
typedef _Float16 h2v __attribute__((ext_vector_type(2)));
typedef float f4 __attribute__((ext_vector_type(4)));
typedef uint32_t u32a __attribute__((may_alias));

// cvt_pkrtz returns __fp16x2; bit-cast to our _Float16x2
__device__ __forceinline__ h2v pkrtz(float a, float b) {
    return __builtin_bit_cast(h2v, __builtin_amdgcn_cvt_pkrtz(a, b));
}

__device__ __forceinline__ float wave_sum(float v) {
    v += __shfl_down(v, 32, 64);
    v += __shfl_down(v, 16, 64);
    v += __shfl_down(v, 8, 64);
    v += __shfl_down(v, 4, 64);
    v += __shfl_down(v, 2, 64);
    v += __shfl_down(v, 1, 64);
    return v;
}

// ---------------- kernel 0: extract feature index from one-hot W1 ----------
__global__ void feat_kernel(const float* __restrict__ W1, int* __restrict__ feat) {
    const int row = blockIdx.x * 4 + (threadIdx.x >> 6);
    const int lane = threadIdx.x & 63;
    const float4* r = reinterpret_cast<const float4*>(W1 + (size_t)row * MM);
    float4 a = r[lane];
    float4 b = r[lane + 64];
    float ba = (float)(4 * lane);
    float bb = (float)(4 * (lane + 64));
    float acc = 0.0f;
    acc = fmaf(a.x, ba,        acc);
    acc = fmaf(a.y, ba + 1.0f, acc);
    acc = fmaf(a.z, ba + 2.0f, acc);
    acc = fmaf(a.w, ba + 3.0f, acc);
    acc = fmaf(b.x, bb,        acc);
    acc = fmaf(b.y, bb + 1.0f, acc);
    acc = fmaf(b.z, bb + 2.0f, acc);
    acc = fmaf(b.w, bb + 3.0f, acc);
    acc = wave_sum(acc);
    if (lane == 0) feat[row] = (int)(acc + 0.5f);
}

// ---------------- kernel 0b: Cw -> f16 B-frag order in global ws ----------
// cwT[(((t*8+c)*8+cls)*4+slot)*8+j] = Cw[t][c*32+slot*8+j][cls]  (256 KB)
__global__ void cwt_kernel(const float* __restrict__ Cw, _Float16* __restrict__ cwT) {
    int idx = blockIdx.x * 256 + threadIdx.x;   // t*256 + k
    int t = idx >> 8, k = idx & 255;
    int c = k >> 5, sl = (k >> 3) & 3, j = k & 7;
    const float4* p = reinterpret_cast<const float4*>(Cw + (size_t)idx * CC);
    float4 p0 = p[0], p1 = p[1];
    _Float16* base = cwT + ((((t * 8 + c) * 8) * 4 + sl) * 8 + j);  // cls stride 32
    base[0 * 32] = (_Float16)p0.x;
    base[1 * 32] = (_Float16)p0.y;
    base[2 * 32] = (_Float16)p0.z;
    base[3 * 32] = (_Float16)p0.w;
    base[4 * 32] = (_Float16)p1.x;
    base[5 * 32] = (_Float16)p1.y;
    base[6 * 32] = (_Float16)p1.z;
    base[7 * 32] = (_Float16)p1.w;
}

// s = sigmoid(10*(xv+b)) = 1/(1+2^(-10*log2(e)*(xv+b))); c1 = -14.4269504*b
__device__ __forceinline__ float sigm_from(float xv, float c1) {
    float earg = fmaf(-14.426950408889634f, xv, c1);
    float e = exp2f(earg);
    return __builtin_amdgcn_rcpf(1.0f + e);
}

// ---------------- kernel 1: forest forward, wave-autonomous + MFMA --------
// R10 ordering discipline (asm fences: R11 lesson — u32 writes vs f16 reads
// are "no-alias" under TBAA, so WITHOUT fences the compiler reorders staging
// writes across path reads -> NaN) + R11 optimizations: b128 xsi gather
// (8 read-ops/tree, was 32), rolling feat/b1 prefetch, early cwT loads
// (vmcnt counter -> unaffected by the lgkm fence). LDS 53,248 B -> 3 blk/CU.
// A-frag: row=lane&15, k=(lane>>4)*8+j [m120]; D: col=lane&15, row=quad*4+reg.
__global__ __launch_bounds__(256, 2) void forest_kernel(
        const float* __restrict__ x, const float* __restrict__ b1,
        const _Float16* __restrict__ cwT, const int* __restrict__ feat,
        float* __restrict__ out) {
    __shared__ __align__(16) _Float16 xsi[MM * XS];     // 16384 B
    __shared__ _Float16 s8[4][256 * ST];                // 36864 B
    // red[4][64] f4 aliased into xsi at epilogue (after full-block barrier)

    const int tid = threadIdx.x;
    const int w = tid >> 6;
    const int lane = tid & 63;
    const int b0 = blockIdx.x * RB;
    const int t0 = blockIdx.y * TPB;
    const int m = lane & 15;     // MFMA row (A) / class col (B) index
    const int slot = lane >> 4;  // MFMA k-slot

    // ---- xsi fill: coalesced global reads; one-time LDS scatter ----
    for (int idx = tid; idx < MM * RB; idx += 256) {
        int mm = idx & (MM - 1);
        int r = idx >> 9;
        xsi[mm * XS + r] = (_Float16)x[(size_t)(b0 + r) * MM + mm];
    }
    __syncthreads();   // barrier #1

    _Float16* s8w = s8[w];

    const int b3 = slot >> 1, b4 = slot & 1;
    const float sg3 = (float)(2 * b3 - 1), off3 = (float)(1 - b3);
    const float sg4 = (float)(2 * b4 - 1), off4 = (float)(1 - b4);

    f4 acc = {0.f, 0.f, 0.f, 0.f};

    auto ldmeta = [&](int t, int kq, int& f, float& c1) {
        int d = kq * 64 + lane;
        int idx = t * DD + (d < DD ? d : 0);
        f = feat[idx];
        c1 = -14.426950408889634f * b1[idx];
    };

    int fcur[4]; float ccur[4];
    #pragma unroll
    for (int kq = 0; kq < 4; ++kq) ldmeta(t0 + w * 4, kq, fcur[kq], ccur[kq]);

    #pragma unroll
    for (int tt = 0; tt < 4; ++tt) {
        const int t = t0 + w * 4 + tt;

        // WAR fence: block compiler from hoisting this tree's staging writes
        // above the previous tree's path reads (TBAA won't see the alias).
        asm volatile("" ::: "memory");

        // ---- early B-frag loads (global, L2-resident; consumed post-staging;
        //      vmcnt-tracked, unaffected by the lgkm fence below) ----
        h8 bfr[8] = {};
        if (m < CC) {
            const h8* cp = reinterpret_cast<const h8*>(cwT) +
                           (((t * 8 + 0) * 8 + m) * 4 + slot);
            #pragma unroll
            for (int c = 0; c < 8; ++c) bfr[c] = cp[c * 32];  // chunk stride 32 h8
        }

        // ---- rolling prefetch of next tree's feat/b1 ----
        int fnxt[4]; float cnxt[4];
        #pragma unroll
        for (int kq = 0; kq < 4; ++kq) { fnxt[kq] = fcur[kq]; cnxt[kq] = ccur[kq]; }
        if (tt < 3) {
            #pragma unroll
            for (int kq = 0; kq < 4; ++kq) ldmeta(t + 1, kq, fnxt[kq], cnxt[kq]);
        }

        // ---- sigmoid staging: b128 xsi gather -> b32 s8 writes ----
        #pragma unroll
        for (int kq = 0; kq < 4; ++kq) {
            int d = kq * 64 + lane;
            if (d < DD) {
                const float4* xp = reinterpret_cast<const float4*>(xsi + fcur[kq] * XS);
                float4 A = xp[0], Bv = xp[1];
                float c1 = ccur[kq];
                u32a* sp = reinterpret_cast<u32a*>(s8w + d * ST);
                uint32_t raw[8] = {
                    __builtin_bit_cast(uint32_t, A.x), __builtin_bit_cast(uint32_t, A.y),
                    __builtin_bit_cast(uint32_t, A.z), __builtin_bit_cast(uint32_t, A.w),
                    __builtin_bit_cast(uint32_t, Bv.x), __builtin_bit_cast(uint32_t, Bv.y),
                    __builtin_bit_cast(uint32_t, Bv.z), __builtin_bit_cast(uint32_t, Bv.w)};
                #pragma unroll
                for (int i2 = 0; i2 < 8; ++i2) {
                    h2v u = __builtin_bit_cast(h2v, raw[i2]);
                    float sa = sigm_from((float)u.x, c1);
                    float sb = sigm_from((float)u.y, c1);
                    sp[i2] = __builtin_bit_cast(uint32_t, pkrtz(sa, sb));
                }
            }
        }
        // RAW fence: staging writes land before path reads issue.
        asm volatile("s_waitcnt lgkmcnt(0)" ::: "memory");

        // ---- depth-0..2 prefix products (8 of them, one per chunk) ----
        float s0 = (float)s8w[0 * ST + m];
        float s1 = (float)s8w[1 * ST + m];
        float s2 = (float)s8w[2 * ST + m];
        float s3 = (float)s8w[3 * ST + m];
        float s4 = (float)s8w[4 * ST + m];
        float s5p = (float)s8w[5 * ST + m];
        float s6 = (float)s8w[6 * ST + m];
        float P10 = 1.0f - s0, P11 = s0;
        float P200 = P10 * (1.0f - s1), P201 = P10 * s1;
        float P210 = P11 * (1.0f - s2), P211 = P11 * s2;
        float P3a[8];
        P3a[0] = P200 * (1.0f - s3); P3a[1] = P200 * s3;
        P3a[2] = P201 * (1.0f - s4); P3a[3] = P201 * s4;
        P3a[4] = P210 * (1.0f - s5p); P3a[5] = P210 * s5p;
        P3a[6] = P211 * (1.0f - s6); P3a[7] = P211 * s6;

        // ---- 8 chunks: DFS expand levels 3..7, emit A-frag, MFMA ----
        #pragma unroll
        for (int c = 0; c < 8; ++c) {
            const int n3 = 7 + c;                       // depth-3 node (compile-time)
            float sc3 = (float)s8w[n3 * ST + m];
            float f3 = fmaf(sg3, sc3, off3);
            int n4 = 2 * n3 + 1 + b3;
            float sc4 = (float)s8w[n4 * ST + m];
            float f4v = fmaf(sg4, sc4, off4);
            float P5 = P3a[c] * f3 * f4v;
            int n5 = 2 * n4 + 1 + b4;                   // octet root (depth 5)
            float s5 = (float)s8w[n5 * ST + m];
            float v1 = P5 * s5, v0 = P5 - v1;
            int q0 = 2 * n5 + 1;
            float sq0 = (float)s8w[q0 * ST + m];
            float sq1 = (float)s8w[(q0 + 1) * ST + m];
            float w01 = v0 * sq0, w00 = v0 - w01;
            float w11 = v1 * sq1, w10 = v1 - w11;
            int r0 = 2 * q0 + 1;                        // 4 consecutive depth-7 nodes
            float sr0 = (float)s8w[(r0 + 0) * ST + m];
            float sr1 = (float)s8w[(r0 + 1) * ST + m];
            float sr2 = (float)s8w[(r0 + 2) * ST + m];
            float sr3 = (float)s8w[(r0 + 3) * ST + m];
            float l1 = w00 * sr0, l0 = w00 - l1;
            float l3 = w01 * sr1, l2 = w01 - l3;
            float l5 = w10 * sr2, l4 = w10 - l5;
            float l7 = w11 * sr3, l6 = w11 - l7;
            union { h8 v; h2v p[4]; } U;
            U.p[0] = pkrtz(l0, l1);
            U.p[1] = pkrtz(l2, l3);
            U.p[2] = pkrtz(l4, l5);
            U.p[3] = pkrtz(l6, l7);
            acc = __builtin_amdgcn_mfma_f32_16x16x32_f16(U.v, bfr[c], acc, 0, 0, 0);
        }

        #pragma unroll
        for (int kq = 0; kq < 4; ++kq) { fcur[kq] = fnxt[kq]; ccur[kq] = cnxt[kq]; }
    }

    // ---- cross-wave reduction; red aliased into xsi (dead after main loop) ----
    __syncthreads();   // all waves done with xsi/s8 before alias write
    f4* red = reinterpret_cast<f4*>(xsi);
    red[w * 64 + lane] = acc;
    __syncthreads();   // barrier #2
    if (tid < 64) {
        f4 sum = red[0 * 64 + tid];
        sum += red[1 * 64 + tid];
        sum += red[2 * 64 + tid];
        sum += red[3 * 64 + tid];
        int n = tid & 15, sl = tid >> 4;
        if (n < CC) {
            #pragma unroll
            for (int reg = 0; reg < 4; ++reg) {
                int row = sl * 4 + reg;                  // D: row=(lane>>4)*4+reg
                atomicAdd(&out[(size_t)(b0 + row) * CC + n], sum[reg] * (1.0f / 64.0f));
            }
        }
    }
}

extern "C" void kernel_launch(void* const* d_in, const int* in_sizes, int n_in,
                              void* d_out, int out_size, void* d_ws, size_t ws_size,
                              hipStream_t stream) {
    const float* x  = (const float*)d_in[0];  // [B, M]
    const float* W1 = (const float*)d_in[1];  // [T, D, M] one-hot rows
    const float* b1 = (const float*)d_in[2];  // [T, D]
    // d_in[3] = Bpos, d_in[4] = Bneg: fixed complete-tree path masks (hardcoded)
    const float* Cw = (const float*)d_in[5];  // [T, K, C]
    float* out = (float*)d_out;               // [B, C] fp32

    // ws layout: cwT f16 [256 KB] | feat int [65 KB]  (rebuilt every call)
    _Float16* cwT = (_Float16*)d_ws;
    int* feat = (int*)((char*)d_ws + (size_t)TT * KK * CC * sizeof(_Float16));

    (void)hipMemsetAsync(out, 0, (size_t)BB * CC * sizeof(float), stream);
    feat_kernel<<<(TT * DD) / 4, 256, 0, stream>>>(W1, feat);
    cwt_kernel<<<(TT * KK) / 256, 256, 0, stream>>>(Cw, cwT);
    forest_kernel<<<dim3(BB / RB, TT / TPB), 256, 0, stream>>>(x, b1, cwT, feat, out);
}